// Round 1
// baseline (109.332 us; speedup 1.0000x reference)
//
#include <hip/hip_runtime.h>

// K-winners-take-all: per row of [4096, 8192] f32, exactly k=410 largest -> 1.0, rest 0.0.
// Ties at the k-th value broken by LOWER index (jax.lax.top_k stable semantics).
//
// One 256-thread block per row:
//  1. load row -> order-preserving uint32 keys in LDS (32KB)
//  2. 4x 8-bit radix-select passes (LDS histograms, per-wave replicated) -> exact
//     key T of the k-th largest, and kk = #winners among elements == T
//  3. equal-to-T indices collected to small LDS list; winner iff (#equals with
//     smaller index) < kk
//  4. coalesced float4 mask write

#define E      8192
#define BLK    256
#define PER    32          // E / BLK
#define KACT   410         // ceil(0.05 * 8192)

__device__ __forceinline__ unsigned f2ord(unsigned u) {
    // order-preserving float->uint map (larger float => larger key)
    return (u & 0x80000000u) ? ~u : (u | 0x80000000u);
}

__global__ __launch_bounds__(BLK, 4)
void kwta_kernel(const float* __restrict__ x, float* __restrict__ out) {
    __shared__ __align__(16) unsigned keys[E];   // 32 KB
    __shared__ unsigned hist[4][257];            // per-wave replicas, 257 pad -> distinct banks
    __shared__ unsigned sufx[257];
    __shared__ unsigned bbin, bkk;
    __shared__ unsigned eqn;
    __shared__ unsigned eqidx[64];

    const int t    = threadIdx.x;
    const int wave = t >> 6;
    const size_t rowbase = (size_t)blockIdx.x * (size_t)E;

    // ---- 1. load + convert (coalesced uint4) ----
    const uint4* xin = reinterpret_cast<const uint4*>(x + rowbase);
    uint4* kq = reinterpret_cast<uint4*>(keys);
    #pragma unroll
    for (int it = 0; it < PER / 4; ++it) {
        int idx = it * BLK + t;                  // float4 index within row
        uint4 v = xin[idx];
        uint4 kv;
        kv.x = f2ord(v.x); kv.y = f2ord(v.y); kv.z = f2ord(v.z); kv.w = f2ord(v.w);
        kq[idx] = kv;
    }
    if (t == 0) eqn = 0u;
    __syncthreads();

    // ---- 2. radix select: find exact key T of the KACT-th largest ----
    unsigned prefix = 0u;   // fixed high bits of T so far
    unsigned kk     = KACT; // winners still to pick among current candidates
    for (int shift = 24; shift >= 0; shift -= 8) {
        const unsigned fixedmask = (shift == 24) ? 0u : (0xFFFFFFFFu << (shift + 8));

        for (int i = t; i < 4 * 257; i += BLK) (&hist[0][0])[i] = 0u;
        __syncthreads();

        for (int it = 0; it < PER; ++it) {       // conflict-free interleaved LDS reads
            unsigned key = keys[it * BLK + t];
            if ((key & fixedmask) == prefix)
                atomicAdd(&hist[wave][(key >> shift) & 255u], 1u);
        }
        __syncthreads();

        sufx[t] = hist[0][t] + hist[1][t] + hist[2][t] + hist[3][t];
        __syncthreads();
        // inclusive suffix sum over 256 bins (Hillis-Steele, 8 steps)
        for (int d = 1; d < 256; d <<= 1) {
            unsigned add = (t + d < 256) ? sufx[t + d] : 0u;
            __syncthreads();
            sufx[t] += add;
            __syncthreads();
        }
        unsigned sb  = sufx[t];
        unsigned sb1 = (t < 255) ? sufx[t + 1] : 0u;
        // unique bin b with sufx[b] >= kk > sufx[b+1]
        if (sb >= kk && sb1 < kk) { bbin = (unsigned)t; bkk = kk - sb1; }
        __syncthreads();
        prefix |= (bbin << shift);
        kk = bkk;
        __syncthreads();
    }
    const unsigned T = prefix;  // exact key of k-th largest; kk = winners among ==T

    // ---- 3. collect indices equal to T (rare; usually 1) ----
    for (int it = 0; it < PER; ++it) {
        int e = it * BLK + t;
        if (keys[e] == T) {
            unsigned p = atomicAdd(&eqn, 1u);
            if (p < 64u) eqidx[p] = (unsigned)e;
        }
    }
    __syncthreads();
    const unsigned m = eqn;

    // ---- 4. coalesced mask write ----
    float4* o = reinterpret_cast<float4*>(out + rowbase);
    #pragma unroll
    for (int it = 0; it < PER / 4; ++it) {
        int idx = it * BLK + t;
        uint4 kv = kq[idx];
        unsigned ks[4] = {kv.x, kv.y, kv.z, kv.w};
        float rs[4];
        #pragma unroll
        for (int j = 0; j < 4; ++j) {
            unsigned key = ks[j];
            float val = 0.0f;
            if (key > T) {
                val = 1.0f;
            } else if (key == T) {
                unsigned e = (unsigned)(idx * 4 + j);
                unsigned cnt = 0u;
                if (m <= 64u) {
                    for (unsigned i = 0; i < m; ++i) cnt += (eqidx[i] < e) ? 1u : 0u;
                } else {
                    // overflow fallback (adversarial data only): scan row
                    for (unsigned i = 0; i < e; ++i) cnt += (keys[i] == T) ? 1u : 0u;
                }
                val = (cnt < kk) ? 1.0f : 0.0f;   // lower-index equals win
            }
            rs[j] = val;
        }
        float4 r; r.x = rs[0]; r.y = rs[1]; r.z = rs[2]; r.w = rs[3];
        o[idx] = r;
    }
}

extern "C" void kernel_launch(void* const* d_in, const int* in_sizes, int n_in,
                              void* d_out, int out_size, void* d_ws, size_t ws_size,
                              hipStream_t stream) {
    const float* x = (const float*)d_in[0];
    float* out = (float*)d_out;
    const int rows = in_sizes[0] / E;            // 4096
    kwta_kernel<<<dim3(rows), dim3(BLK), 0, stream>>>(x, out);
}

// Round 2
// 66.263 us; speedup vs baseline: 1.6500x; 1.6500x over previous
//
#include <hip/hip_runtime.h>

// K-winners-take-all: per row of [4096, 8192] f32, exactly k=410 largest -> 1.0.
// Ties at the k-th value broken by LOWER index (jax.lax.top_k stable semantics).
//
// R2 design: row lives in REGISTERS (8 x uint4 per thread), no LDS copy.
//  1. load + order-preserving key convert; count vs 4 fixed pivots in regs
//  2. pick largest pivot with count >= k (N(0,1): 1.5 -> ~547 candidates);
//     fallback = no filter (rare, still exact)
//  3. 4x 8-bit radix-select over register keys, filtered to key > pivot:
//     ~550 LDS atomics/pass instead of 8192; single-wave shfl suffix-scan
//     (2 barriers/pass instead of 18)
//  4. exact tie-break via per-thread equals-bitmask in LDS (handles any m)
//  5. coalesced float4 mask write from registers

#define E     8192
#define BLK   256
#define KACT  410
#define NW    4

__device__ __forceinline__ unsigned f2ord(unsigned u) {
    // order-preserving float->uint map (larger float => larger key)
    return (u & 0x80000000u) ? ~u : (u | 0x80000000u);
}

// rank of equal-element (it,j) of thread t among all equals, by ascending index.
// element index e = it*1024 + t*4 + j ; eqmask[t'] bit (it'*4+j') marks equals.
__device__ __noinline__ unsigned eq_rank(const unsigned* eqmask, int t, int it, int j) {
    const unsigned m_lt = (2u << (4 * it + 3)) - 1u;   // groups <= it fully
    const unsigned m_eq = (1u << (4 * it + j)) - 1u;   // own slots below (it,j)
    const unsigned m_gt = (1u << (4 * it)) - 1u;       // groups < it only
    unsigned cnt = 0;
    for (int tp = 0; tp < BLK; ++tp) {
        unsigned em = eqmask[tp];
        unsigned msk = (tp < t) ? m_lt : ((tp == t) ? m_eq : m_gt);
        cnt += __popc(em & msk);
    }
    return cnt;
}

__global__ __launch_bounds__(BLK, 4)
void kwta_kernel(const float* __restrict__ x, float* __restrict__ out) {
    __shared__ unsigned hist[NW][257];
    __shared__ unsigned psum01[NW], psum23[NW], psum_m[NW];
    __shared__ unsigned eqmask[BLK];
    __shared__ unsigned s_prefix, s_kk;

    const int t    = threadIdx.x;
    const int lane = t & 63;
    const int wave = t >> 6;
    const size_t rowbase = (size_t)blockIdx.x * (size_t)E;
    const uint4* xin = reinterpret_cast<const uint4*>(x + rowbase);

    if (t == 0) { s_prefix = 0u; s_kk = KACT; }
    for (int i = t; i < NW * 257; i += BLK) (&hist[0][0])[i] = 0u;

    // ---- 1. load -> registers, convert, count vs fixed pivots ----
    const unsigned PK0 = 0xC0000000u;  // f2ord(2.0f)
    const unsigned PK1 = 0xBFC00000u;  // f2ord(1.5f)
    const unsigned PK2 = 0xBF800000u;  // f2ord(1.0f)
    const unsigned PK3 = 0xBF000000u;  // f2ord(0.5f)

    uint4 kv[8];
    unsigned c0 = 0, c1 = 0, c2 = 0, c3 = 0;
    #pragma unroll
    for (int it = 0; it < 8; ++it) {
        uint4 v = xin[it * BLK + t];
        uint4 k;
        k.x = f2ord(v.x); k.y = f2ord(v.y); k.z = f2ord(v.z); k.w = f2ord(v.w);
        kv[it] = k;
        c0 += (k.x > PK0) + (k.y > PK0) + (k.z > PK0) + (k.w > PK0);
        c1 += (k.x > PK1) + (k.y > PK1) + (k.z > PK1) + (k.w > PK1);
        c2 += (k.x > PK2) + (k.y > PK2) + (k.z > PK2) + (k.w > PK2);
        c3 += (k.x > PK3) + (k.y > PK3) + (k.z > PK3) + (k.w > PK3);
    }
    unsigned p01 = (c0 & 0xFFFFu) | (c1 << 16);
    unsigned p23 = (c2 & 0xFFFFu) | (c3 << 16);
    #pragma unroll
    for (int d = 1; d < 64; d <<= 1) {
        p01 += __shfl_down(p01, d);
        p23 += __shfl_down(p23, d);
    }
    if (lane == 0) { psum01[wave] = p01; psum23[wave] = p23; }
    __syncthreads();

    // ---- 2. choose pivot (largest with count >= k) ----
    const unsigned t01 = psum01[0] + psum01[1] + psum01[2] + psum01[3];
    const unsigned t23 = psum23[0] + psum23[1] + psum23[2] + psum23[3];
    const unsigned n0 = t01 & 0xFFFFu, n1 = t01 >> 16;
    const unsigned n2 = t23 & 0xFFFFu, n3 = t23 >> 16;
    unsigned pk; bool nofilter = false;
    if      (n0 >= KACT) pk = PK0;
    else if (n1 >= KACT) pk = PK1;
    else if (n2 >= KACT) pk = PK2;
    else if (n3 >= KACT) pk = PK3;
    else { pk = 0u; nofilter = true; }   // pathological rows: full radix, exact

    // ---- 3. radix select over register keys (filtered) ----
    #pragma unroll 1
    for (int shift = 24; shift >= 0; shift -= 8) {
        const unsigned fixedmask = (shift == 24) ? 0u : (0xFFFFFFFFu << (shift + 8));
        const unsigned pref = s_prefix;
        #pragma unroll
        for (int it = 0; it < 8; ++it) {
            uint4 k = kv[it];
            unsigned ka[4] = {k.x, k.y, k.z, k.w};
            #pragma unroll
            for (int j = 0; j < 4; ++j) {
                unsigned key = ka[j];
                if (((key > pk) | nofilter) && ((key & fixedmask) == pref))
                    atomicAdd(&hist[wave][(key >> shift) & 255u], 1u);
            }
        }
        __syncthreads();
        if (wave == 0) {
            const int b = lane * 4;
            unsigned h0 = hist[0][b]     + hist[1][b]     + hist[2][b]     + hist[3][b];
            unsigned h1 = hist[0][b + 1] + hist[1][b + 1] + hist[2][b + 1] + hist[3][b + 1];
            unsigned h2 = hist[0][b + 2] + hist[1][b + 2] + hist[2][b + 2] + hist[3][b + 2];
            unsigned h3 = hist[0][b + 3] + hist[1][b + 3] + hist[2][b + 3] + hist[3][b + 3];
            unsigned local = h0 + h1 + h2 + h3;
            unsigned run = local;
            #pragma unroll
            for (int d = 1; d < 64; d <<= 1) {
                unsigned o = __shfl_down(run, d);
                run += (lane + d < 64) ? o : 0u;
            }
            const unsigned tail = run - local;          // suffix over higher lanes
            const unsigned kk = s_kk;
            const unsigned s3 = tail + h3;
            const unsigned s2 = s3 + h2;
            const unsigned s1 = s2 + h1;
            const unsigned s0 = s1 + h0;
            unsigned nb = 0, nk = 0; bool f = false;
            if      (s0 >= kk && s1   < kk) { f = true; nb = b + 0; nk = kk - s1; }
            else if (s1 >= kk && s2   < kk) { f = true; nb = b + 1; nk = kk - s2; }
            else if (s2 >= kk && s3   < kk) { f = true; nb = b + 2; nk = kk - s3; }
            else if (s3 >= kk && tail < kk) { f = true; nb = b + 3; nk = kk - tail; }
            if (f) { s_prefix = pref | (nb << shift); s_kk = nk; }
            for (int i = lane; i < NW * 257; i += 64) (&hist[0][0])[i] = 0u;  // re-zero
        }
        __syncthreads();
    }
    const unsigned T  = s_prefix;   // exact key of k-th largest
    const unsigned kk = s_kk;       // winners among elements == T

    // ---- 4. equals bitmask for exact index-ordered tie-break ----
    unsigned myeq = 0u;
    #pragma unroll
    for (int it = 0; it < 8; ++it) {
        uint4 k = kv[it];
        myeq |= (k.x == T ? 1u : 0u) << (it * 4 + 0);
        myeq |= (k.y == T ? 1u : 0u) << (it * 4 + 1);
        myeq |= (k.z == T ? 1u : 0u) << (it * 4 + 2);
        myeq |= (k.w == T ? 1u : 0u) << (it * 4 + 3);
    }
    eqmask[t] = myeq;
    unsigned pm = __popc(myeq);
    #pragma unroll
    for (int d = 1; d < 64; d <<= 1) pm += __shfl_down(pm, d);
    if (lane == 0) psum_m[wave] = pm;
    __syncthreads();
    const unsigned m = psum_m[0] + psum_m[1] + psum_m[2] + psum_m[3];
    const bool allwin = (kk == m);   // common case: every tied element wins

    // ---- 5. coalesced mask write from registers ----
    float4* o = reinterpret_cast<float4*>(out + rowbase);
    #pragma unroll
    for (int it = 0; it < 8; ++it) {
        uint4 k = kv[it];
        unsigned ka[4] = {k.x, k.y, k.z, k.w};
        float rs[4];
        #pragma unroll
        for (int j = 0; j < 4; ++j) {
            unsigned key = ka[j];
            float val;
            if (key > T)       val = 1.0f;
            else if (key != T) val = 0.0f;
            else if (allwin)   val = 1.0f;
            else               val = (eq_rank(eqmask, t, it, j) < kk) ? 1.0f : 0.0f;
            rs[j] = val;
        }
        float4 r; r.x = rs[0]; r.y = rs[1]; r.z = rs[2]; r.w = rs[3];
        o[it * BLK + t] = r;
    }
}

extern "C" void kernel_launch(void* const* d_in, const int* in_sizes, int n_in,
                              void* d_out, int out_size, void* d_ws, size_t ws_size,
                              hipStream_t stream) {
    const float* x = (const float*)d_in[0];
    float* out = (float*)d_out;
    const int rows = in_sizes[0] / E;   // 4096
    kwta_kernel<<<dim3(rows), dim3(BLK), 0, stream>>>(x, out);
}